// Round 16
// baseline (90.415 us; speedup 1.0000x reference)
//
#include <hip/hip_runtime.h>
#include <hip/hip_bf16.h>

// Problem constants
#define BB 4
#define LL 1024
#define NFE 480
#define HH 32
#define FCC 512
#define DD 512
#define WW 65
#define BL (BB*LL)          // 4096
#define BLH (BL*HH)         // 131072
#define LPAD 1088           // 1024 + 2*32 halo

typedef short bf16x8 __attribute__((ext_vector_type(8)));
typedef float f32x16 __attribute__((ext_vector_type(16)));
typedef unsigned short us8 __attribute__((ext_vector_type(8)));

__device__ inline unsigned short f2bf(float x) {
    union { float f; unsigned u; } v; v.f = x;
    unsigned r = v.u + 0x7FFFu + ((v.u >> 16) & 1u);
    return (unsigned short)(r >> 16);
}

// Static device scratch
__device__ __align__(16) unsigned short g_oefb[BL*FCC];   // bf16 concat(x_embeds, cls)
__device__ __align__(16) unsigned short g_knt[2*DD*FCC];  // bf16 knn^T [z][n][k]
__device__ float  g_m[BL];
__device__ __align__(16) unsigned short g_fpad[2*BB*LPAD*DD];   // bf16 cf0/cf1, zero-padded rows
__device__ __align__(16) unsigned short g_kb2[(size_t)3*WW*4*8*64*8]; // conv k in B-frag order
__device__ __align__(16) unsigned short g_kbs[4*4*8*64*8];      // small-GEMM B in frag order
__device__ float  g_actsp[8][3*BLH];    // per-(dq,hh) partials
__device__ float  g_small[4*BLH];
__device__ float  g_gt[HH*LL];          // TRANSPOSED: gt_t[d][h], h contiguous
__device__ float  g_vsum4[4][BLH];      // per-window-quarter partials

// ================ KPREP: fused prep (R14, unchanged) ================
__global__ __launch_bounds__(256) void kprep(const float* __restrict__ x_embeds,
                                             const float* __restrict__ latent,
                                             const float* __restrict__ masks,
                                             const float* __restrict__ x,
                                             const float* __restrict__ ampl,
                                             const float* __restrict__ inp,
                                             const float* __restrict__ outv,
                                             const float* __restrict__ pos,
                                             const float* __restrict__ bias,
                                             const float* __restrict__ pdw,
                                             const float* __restrict__ knn) {
    const int bx = blockIdx.x;
    const int tid = threadIdx.x;

    if (bx < 512) {                    // ---- k1: softmax + concat + m ----
        const int row0 = bx * 8;
        const int r    = row0 + (tid >> 5);
        const int lane = tid & 31;

        const float mask = masks[r];
        float v = latent[r*HH + lane] * mask;
        float mx = v;
        #pragma unroll
        for (int off = 16; off > 0; off >>= 1) mx = fmaxf(mx, __shfl_xor(mx, off, 32));
        float e = __expf(v - mx);
        float s = e;
        #pragma unroll
        for (int off = 16; off > 0; off >>= 1) s += __shfl_xor(s, off, 32);
        g_oefb[r*FCC + NFE + lane] = f2bf(e / s * mask);

        if (lane == 0) g_m[r] = mask + x[r*23 + 21] + x[r*23 + 22];

        for (int idx = tid; idx < 8*NFE; idx += 256) {
            int rr = idx / NFE, c = idx - rr*NFE;
            g_oefb[(row0+rr)*FCC + c] = f2bf(x_embeds[(row0+rr)*NFE + c]);
        }
    } else if (bx < 640) {             // ---- k0: zero g_fpad halos ----
        int idx = (bx - 512) * 256 + tid;
        int fzb = idx >> 12;
        int rem = idx & 4095;
        int rowi = rem >> 6;
        int col8 = rem & 63;
        int row = (rowi < 32) ? rowi : (1024 + rowi);
        int4 z = make_int4(0,0,0,0);
        *reinterpret_cast<int4*>(&g_fpad[((size_t)fzb*LPAD + row)*DD + col8*8]) = z;
    } else if (bx < 768) {             // ---- k3c: knn -> bf16 transpose ----
        __shared__ unsigned short tile[64][65];
        int idx2 = bx - 640;
        const int k0 = (idx2 & 7) * 64;
        const int n0 = ((idx2 >> 3) & 7) * 64;
        const int z  = idx2 >> 6;
        const float* __restrict__ src = knn + (size_t)z*FCC*DD;
        #pragma unroll 4
        for (int i = 0; i < 16; ++i) {
            int idx = i*256 + tid;
            int kk = idx >> 6, nn = idx & 63;
            tile[kk][nn] = f2bf(src[(size_t)(k0+kk)*DD + n0+nn]);
        }
        __syncthreads();
        #pragma unroll 4
        for (int i = 0; i < 16; ++i) {
            int idx = i*256 + tid;
            int nn = idx >> 6, kk = idx & 63;
            g_knt[((size_t)z*DD + n0+nn)*FCC + k0+kk] = tile[kk][nn];
        }
    } else if (bx < 800) {             // ---- k3d: small-GEMM B frags ----
        int t = (bx - 768)*256 + tid;
        int lane = t & 63;
        int ks = (t >> 6) & 7;
        int dt = (t >> 9) & 3;
        int o  = t >> 11;
        int l31 = lane & 31, khalf = lane >> 5;
        const float* S = (o == 0) ? ampl + 1*DD*HH :
                         (o == 1) ? ampl + 3*DD*HH :
                         (o == 2) ? ampl + 4*DD*HH : pdw;
        int k0 = dt*128 + ks*16 + khalf*8;
        us8 outw;
        #pragma unroll
        for (int i = 0; i < 8; ++i) outw[i] = f2bf(S[(size_t)(k0+i)*HH + l31]);
        *reinterpret_cast<us8*>(&g_kbs[(size_t)t*8]) = outw;
    } else if (bx < 928) {             // ---- k3b: gt_t[d][h] (transposed) ----
        int idx = (bx - 800) * 256 + tid;   // < 32768
        int h = idx & 31;
        int dist = idx >> 5;
        float cm = bias[4*HH + h];
        float sig = cm*cm + 1e-4f;
        float dd = (float)dist;
        g_gt[idx] = __expf(-sig * dd * dd);   // g_gt[dist*32 + h]
    } else {                           // ---- k3: conv k in B-frag order ----
        int idx3 = bx - 928;           // 0..1559
        int xi  = idx3 & 7;
        int rem = idx3 >> 3;           // 0..194
        int w   = rem % 65;
        int z   = rem / 65;
        int idx = xi * 256 + tid;      // 0..2047
        const int lane = idx & 63;
        const int ks   = (idx >> 6) & 7;
        const int dt   = idx >> 9;
        const int h    = lane & 31;
        const int d8   = dt*128 + ks*16 + (lane >> 5)*8;

        const float c0 = 0.01f;
        const float p = pos[w];
        int ai, mi, vi;
        if (z == 0)      { ai = 0; mi = 0;  vi = 1; }
        else if (z == 1) { ai = 1; mi = -1; vi = 2; }
        else             { ai = 2; mi = 3;  vi = 4; }

        us8 outw;
        #pragma unroll
        for (int i = 0; i < 8; ++i) {
            int d = d8 + i;
            float a    = ampl[(size_t)ai*DD*HH + d*HH + h];
            float mean = (mi >= 0) ? inp[mi*DD + d] * outv[mi*HH + h] : 0.f;
            float iv   = fabsf(inp[vi*DD + d] * outv[vi*HH + h]) + c0;
            float tt = p - mean;
            outw[i] = f2bf(__expf(-iv * tt * tt) * a);
        }
        *reinterpret_cast<us8*>(&g_kb2[((((size_t)z*WW + w)*4 + dt)*8 + ks)*512 + (size_t)lane*8]) = outw;
    }
}

// ================ K2: cf0/cf1 via MFMA (R14, unchanged) ================
__global__ __launch_bounds__(256) void k2_mfma() {
    const int nt = blockIdx.x;
    const int mt = blockIdx.y;
    const int z  = blockIdx.z;
    const int t  = threadIdx.x;
    const int wave = t >> 6, lane = t & 63;
    const int l31 = lane & 31, khalf = lane >> 5;
    const int n0 = nt*128 + wave*32;
    const int m_base = mt*64;

    __shared__ __align__(16) unsigned short smem[64*128];  // 16 KB A tile (swizzled)

    f32x16 acc[2];
    #pragma unroll
    for (int mti = 0; mti < 2; ++mti)
        #pragma unroll
        for (int i = 0; i < 16; ++i) acc[mti][i] = 0.f;

    const unsigned short* __restrict__ bptr =
        g_knt + ((size_t)z*DD + n0 + l31)*FCC + khalf*8;

    for (int kc = 0; kc < 4; ++kc) {
        __syncthreads();
        const unsigned short* __restrict__ src = g_oefb + (size_t)m_base*FCC + kc*128;
        #pragma unroll
        for (int c = 0; c < 4; ++c) {
            int q = c*256 + t;
            int row = q >> 4, slot = q & 15;
            int4 v = *reinterpret_cast<const int4*>(src + (size_t)row*FCC + slot*8);
            int off = row*256 + ((slot*16) ^ ((row & 15) << 4));
            *reinterpret_cast<int4*>((char*)smem + off) = v;
        }
        __syncthreads();
        #pragma unroll
        for (int ks = 0; ks < 8; ++ks) {
            bf16x8 bf = *reinterpret_cast<const bf16x8*>(bptr + kc*128 + ks*16);
            int dby = ks*32 + khalf*16;
            #pragma unroll
            for (int mti = 0; mti < 2; ++mti) {
                int r = mti*32 + l31;
                bf16x8 a = *reinterpret_cast<const bf16x8*>(
                    (char*)smem + r*256 + (dby ^ ((r & 15) << 4)));
                acc[mti] = __builtin_amdgcn_mfma_f32_32x32x16_bf16(a, bf, acc[mti], 0, 0, 0);
            }
        }
    }

    #pragma unroll
    for (int mti = 0; mti < 2; ++mti) {
        #pragma unroll
        for (int reg = 0; reg < 16; ++reg) {
            int rowf = (reg & 3) + 8*(reg >> 2) + 4*khalf;
            int m = m_base + mti*32 + rowf;
            int b_ = m >> 10, l_ = m & 1023;
            g_fpad[((size_t)(z*BB + b_)*LPAD + 32 + l_)*DD + n0 + l31] = f2bf(acc[mti][reg]);
        }
    }
}

// ================ KHEAVY: k4 (wave=(subtile,whalf)) [0,768) / k6 [768,1280) / k5 [1280,1408) ================
__global__ __launch_bounds__(256) void kheavy() {
    __shared__ __align__(16) char smem_raw[32768];
    const int bx = blockIdx.x;
    const int t  = threadIdx.x;

    if (bx < 768) {
        // ---------- k4: MFMA conv-GEMM; waves pair on identical B sequences ----------
        const int xcd = bx & 7;
        const int j8  = bx >> 3;            // 0..95
        const int gidx = xcd*96 + j8;       // slice-ordered global index (XCD L2 locality)
        const int zdq = gidx >> 6;          // 0..11
        const int g   = gidx & 63;
        const int lt = g & 15;
        const int b  = g >> 4;
        const int z  = zdq >> 2;
        const int dq = zdq & 3;
        const int fz = (z == 1) ? 1 : 0;
        const int wave = t >> 6, lane = t & 63;
        const int l31 = lane & 31, khalf = lane >> 5;
        const int s  = wave & 1;            // m-subtile (rows s*32..s*32+31 of the 64)
        const int hh = wave >> 1;           // w-half
        const int wbeg = hh ? 33 : 0;
        const int wend = hh ? 65 : 33;

        f32x16 acc;
        #pragma unroll
        for (int i = 0; i < 16; ++i) acc[i] = 0.f;

        // stage 128 rows (64 out + 64 halo), cols dq*128..+127
        const unsigned short* src =
            g_fpad + ((size_t)(fz*BB + b)*LPAD + lt*64) * DD + dq*128;
        #pragma unroll
        for (int c = 0; c < 8; ++c) {
            int q = c*256 + t;
            int row = q >> 4, slot = q & 15;
            int4 v = *reinterpret_cast<const int4*>(src + (size_t)row*DD + slot*8);
            int off = row*256 + ((slot*16) ^ ((row & 15) << 4));
            *reinterpret_cast<int4*>(smem_raw + off) = v;
        }
        __syncthreads();

        for (int w = wbeg; w < wend; ++w) {
            const unsigned short* kbw =
                g_kb2 + ((((size_t)z*WW + w)*4 + dq)*8)*512;
            const int rl = s*32 + l31 + w;      // <= 32+31+64 = 127
            const int rbase = rl*256;
            const int rx = (rl & 15) << 4;
            #pragma unroll
            for (int ks = 0; ks < 8; ++ks) {
                bf16x8 bf = *reinterpret_cast<const bf16x8*>(kbw + ks*512 + lane*8);
                int dby = ks*32 + khalf*16;
                bf16x8 a = *reinterpret_cast<const bf16x8*>(
                    smem_raw + rbase + (dby ^ rx));
                acc = __builtin_amdgcn_mfma_f32_32x32x16_bf16(a, bf, acc, 0, 0, 0);
            }
        }

        // direct epilogue: wave owns (slot = dq*2+hh, rows s*32..s*32+31) — no reduction
        float* outp = g_actsp[dq*2 + hh] + (size_t)z*BLH + ((size_t)b*LL + lt*64)*HH;
        #pragma unroll
        for (int reg = 0; reg < 16; ++reg) {
            int rowf = (reg & 3) + 8*(reg >> 2) + 4*khalf;
            outp[(size_t)(s*32 + rowf)*HH + l31] = acc[reg];
        }
    } else if (bx < 1280) {
        // ---------- k6: Toeplitz, b-shared (4 fmaf per gt load), window-quarter split (R14) ----------
        float* mlT = (float*)smem_raw;  // mlT[<=180][4] < 3 KB
        const int g  = bx - 768;
        const int jq = g >> 7;          // 0..3 window quarter
        const int ib = g & 127;
        const int i0 = ib * 8;

        int wlo = i0 - 352; if (wlo < 0) wlo = 0; else wlo &= ~3;
        int whi = i0 + 360; if (whi > 1024) whi = 1024; else whi = (whi + 3) & ~3;
        int qstep = (((whi - wlo) + 15) >> 4) << 2;
        int qlo = wlo + jq*qstep;
        int qhi = qlo + qstep; if (qhi > whi) qhi = whi;
        int qn = qhi - qlo; if (qn < 0) qn = 0;

        for (int idx = t; idx < qn*4; idx += 256) {
            int jj = idx >> 2, b = idx & 3;
            mlT[jj*4 + b] = g_m[b*LL + qlo + jj];
        }
        __syncthreads();

        const int h = t & 31;
        const int i = i0 + (t >> 5);
        const float* __restrict__ gtt = g_gt;
        float a0 = 0.f, a1 = 0.f, a2 = 0.f, a3 = 0.f;
        #pragma unroll 2
        for (int jj = 0; jj < qn; ++jj) {
            int j = qlo + jj;
            int c = i - j; int d = c < 0 ? -c : c;
            float gv = gtt[d*HH + h];
            float4 mv = *reinterpret_cast<const float4*>(&mlT[jj*4]);
            a0 = fmaf(gv, mv.x, a0);
            a1 = fmaf(gv, mv.y, a1);
            a2 = fmaf(gv, mv.z, a2);
            a3 = fmaf(gv, mv.w, a3);
        }
        float* vs = g_vsum4[jq];
        vs[((size_t)(0*LL + i))*HH + h] = a0;
        vs[((size_t)(1*LL + i))*HH + h] = a1;
        vs[((size_t)(2*LL + i))*HH + h] = a2;
        vs[((size_t)(3*LL + i))*HH + h] = a3;
    } else {
        // ---------- k5: small GEMMs via MFMA (R14, unchanged) ----------
        const int g = bx - 1280;
        const int mt = g & 31;
        const int o  = g >> 5;
        const int wave = t >> 6, lane = t & 63;
        const int l31 = lane & 31, khalf = lane >> 5;

        const unsigned short* src;
        if (o == 3) {
            src = g_oefb + (size_t)mt*128*FCC;
        } else {
            const int fz = (o == 1) ? 0 : 1;
            const int m0 = mt*128;
            const int b_ = m0 >> 10, l0 = m0 & 1023;
            src = g_fpad + ((size_t)(fz*BB + b_)*LPAD + 32 + l0)*DD;
        }

        f32x16 acc;
        #pragma unroll
        for (int i = 0; i < 16; ++i) acc[i] = 0.f;

        for (int kc = 0; kc < 4; ++kc) {
            __syncthreads();
            const unsigned short* s2 = src + kc*128;
            #pragma unroll
            for (int c = 0; c < 8; ++c) {
                int q = c*256 + t;
                int row = q >> 4, slot = q & 15;
                int4 v = *reinterpret_cast<const int4*>(s2 + (size_t)row*512 + slot*8);
                int off = row*256 + ((slot*16) ^ ((row & 15) << 4));
                *reinterpret_cast<int4*>(smem_raw + off) = v;
            }
            __syncthreads();
            #pragma unroll
            for (int ks = 0; ks < 8; ++ks) {
                bf16x8 bf = *reinterpret_cast<const bf16x8*>(
                    &g_kbs[((((size_t)o*4 + kc)*8 + ks)*64 + lane)*8]);
                int dby = ks*32 + khalf*16;
                int r = wave*32 + l31;
                bf16x8 a = *reinterpret_cast<const bf16x8*>(
                    smem_raw + r*256 + (dby ^ ((r & 15) << 4)));
                acc = __builtin_amdgcn_mfma_f32_32x32x16_bf16(a, bf, acc, 0, 0, 0);
            }
        }

        float* outp = g_small + (size_t)o*BLH + ((size_t)mt*128 + wave*32)*HH;
        #pragma unroll
        for (int reg = 0; reg < 16; ++reg) {
            int row = (reg & 3) + 8*(reg >> 2) + 4*khalf;
            outp[(size_t)row*HH + l31] = acc[reg];
        }
    }
}

// ================ K7: final combine (8 actsp slots + 4 vsum slots) ================
__global__ __launch_bounds__(256) void k7_final(const float* __restrict__ masks,
                                                const float* __restrict__ bias,
                                                float* __restrict__ out) {
    int idx = blockIdx.x * 256 + threadIdx.x;
    int r = idx >> 5, h = idx & 31;
    float a0 = 0.f, a1 = 0.f, a2 = 0.f;
    #pragma unroll
    for (int s = 0; s < 8; ++s) {
        a0 += g_actsp[s][idx];
        a1 += g_actsp[s][BLH + idx];
        a2 += g_actsp[s][2*BLH + idx];
    }
    float rdf = (a0 + bias[0*HH + h]) * a1
              + a2 * (g_small[idx] + bias[2*HH + h])
              + (g_small[BLH + idx] + bias[1*HH + h]) * g_small[2*BLH + idx];
    float pp = g_small[3*BLH + idx] + bias[3*HH + h];
    float vc = g_m[r] * (g_vsum4[0][idx] + g_vsum4[1][idx] + g_vsum4[2][idx] + g_vsum4[3][idx]);
    out[idx] = vc * pp * rdf * masks[r];
}

extern "C" void kernel_launch(void* const* d_in, const int* in_sizes, int n_in,
                              void* d_out, int out_size, void* d_ws, size_t ws_size,
                              hipStream_t stream) {
    (void)in_sizes; (void)n_in; (void)d_ws; (void)ws_size; (void)out_size;
    const float* x_embeds = (const float*)d_in[0];
    const float* latent   = (const float*)d_in[1];
    const float* masks    = (const float*)d_in[2];
    const float* pos      = (const float*)d_in[3];
    const float* x        = (const float*)d_in[4];
    const float* ampl     = (const float*)d_in[5];
    const float* inp      = (const float*)d_in[6];
    const float* outv     = (const float*)d_in[7];
    const float* bias     = (const float*)d_in[8];
    const float* pdw      = (const float*)d_in[9];
    const float* knn      = (const float*)d_in[10];
    float* out = (float*)d_out;

    hipLaunchKernelGGL(kprep, dim3(2488), dim3(256), 0, stream,
                       x_embeds, latent, masks, x, ampl, inp, outv, pos, bias, pdw, knn);
    hipLaunchKernelGGL(k2_mfma, dim3(4, 64, 2), dim3(256), 0, stream);
    hipLaunchKernelGGL(kheavy, dim3(1408), dim3(256), 0, stream);
    hipLaunchKernelGGL(k7_final, dim3(BLH/256), dim3(256), 0, stream, masks, bias, out);
}

// Round 18
// 83.016 us; speedup vs baseline: 1.0891x; 1.0891x over previous
//
#include <hip/hip_runtime.h>
#include <hip/hip_bf16.h>

// Problem constants
#define BB 4
#define LL 1024
#define NFE 480
#define HH 32
#define FCC 512
#define DD 512
#define WW 65
#define BL (BB*LL)          // 4096
#define BLH (BL*HH)         // 131072
#define LPAD 1088           // 1024 + 2*32 halo

typedef short bf16x8 __attribute__((ext_vector_type(8)));
typedef float f32x16 __attribute__((ext_vector_type(16)));
typedef unsigned short us8 __attribute__((ext_vector_type(8)));

__device__ inline unsigned short f2bf(float x) {
    union { float f; unsigned u; } v; v.f = x;
    unsigned r = v.u + 0x7FFFu + ((v.u >> 16) & 1u);
    return (unsigned short)(r >> 16);
}

// Static device scratch
__device__ __align__(16) unsigned short g_oefb[BL*FCC];   // bf16 concat(x_embeds, cls)
__device__ __align__(16) unsigned short g_knt[2*DD*FCC];  // bf16 knn^T [z][n][k]
__device__ float  g_m[BL];
__device__ __align__(16) unsigned short g_fpad[2*BB*LPAD*DD];   // bf16 cf0/cf1, zero-padded rows
__device__ __align__(16) unsigned short g_kb2[(size_t)3*WW*4*8*64*8]; // conv k in B-frag order
__device__ __align__(16) unsigned short g_kbs[4*4*8*64*8];      // small-GEMM B in frag order
__device__ float  g_actsp[4][3*BLH];    // per-dq partials (waves pre-reduced in-block)
__device__ float  g_small[4*BLH];
__device__ float  g_gt[HH*LL];          // TRANSPOSED: gt_t[d][h], h contiguous
__device__ float  g_vsum4[4][BLH];      // per-window-quarter partials

// ================ KPREP: fused prep (R14, unchanged) ================
__global__ __launch_bounds__(256) void kprep(const float* __restrict__ x_embeds,
                                             const float* __restrict__ latent,
                                             const float* __restrict__ masks,
                                             const float* __restrict__ x,
                                             const float* __restrict__ ampl,
                                             const float* __restrict__ inp,
                                             const float* __restrict__ outv,
                                             const float* __restrict__ pos,
                                             const float* __restrict__ bias,
                                             const float* __restrict__ pdw,
                                             const float* __restrict__ knn) {
    const int bx = blockIdx.x;
    const int tid = threadIdx.x;

    if (bx < 512) {                    // ---- k1: softmax + concat + m ----
        const int row0 = bx * 8;
        const int r    = row0 + (tid >> 5);
        const int lane = tid & 31;

        const float mask = masks[r];
        float v = latent[r*HH + lane] * mask;
        float mx = v;
        #pragma unroll
        for (int off = 16; off > 0; off >>= 1) mx = fmaxf(mx, __shfl_xor(mx, off, 32));
        float e = __expf(v - mx);
        float s = e;
        #pragma unroll
        for (int off = 16; off > 0; off >>= 1) s += __shfl_xor(s, off, 32);
        g_oefb[r*FCC + NFE + lane] = f2bf(e / s * mask);

        if (lane == 0) g_m[r] = mask + x[r*23 + 21] + x[r*23 + 22];

        for (int idx = tid; idx < 8*NFE; idx += 256) {
            int rr = idx / NFE, c = idx - rr*NFE;
            g_oefb[(row0+rr)*FCC + c] = f2bf(x_embeds[(row0+rr)*NFE + c]);
        }
    } else if (bx < 640) {             // ---- k0: zero g_fpad halos ----
        int idx = (bx - 512) * 256 + tid;
        int fzb = idx >> 12;
        int rem = idx & 4095;
        int rowi = rem >> 6;
        int col8 = rem & 63;
        int row = (rowi < 32) ? rowi : (1024 + rowi);
        int4 z = make_int4(0,0,0,0);
        *reinterpret_cast<int4*>(&g_fpad[((size_t)fzb*LPAD + row)*DD + col8*8]) = z;
    } else if (bx < 768) {             // ---- k3c: knn -> bf16 transpose ----
        __shared__ unsigned short tile[64][65];
        int idx2 = bx - 640;
        const int k0 = (idx2 & 7) * 64;
        const int n0 = ((idx2 >> 3) & 7) * 64;
        const int z  = idx2 >> 6;
        const float* __restrict__ src = knn + (size_t)z*FCC*DD;
        #pragma unroll 4
        for (int i = 0; i < 16; ++i) {
            int idx = i*256 + tid;
            int kk = idx >> 6, nn = idx & 63;
            tile[kk][nn] = f2bf(src[(size_t)(k0+kk)*DD + n0+nn]);
        }
        __syncthreads();
        #pragma unroll 4
        for (int i = 0; i < 16; ++i) {
            int idx = i*256 + tid;
            int nn = idx >> 6, kk = idx & 63;
            g_knt[((size_t)z*DD + n0+nn)*FCC + k0+kk] = tile[kk][nn];
        }
    } else if (bx < 800) {             // ---- k3d: small-GEMM B frags ----
        int t = (bx - 768)*256 + tid;
        int lane = t & 63;
        int ks = (t >> 6) & 7;
        int dt = (t >> 9) & 3;
        int o  = t >> 11;
        int l31 = lane & 31, khalf = lane >> 5;
        const float* S = (o == 0) ? ampl + 1*DD*HH :
                         (o == 1) ? ampl + 3*DD*HH :
                         (o == 2) ? ampl + 4*DD*HH : pdw;
        int k0 = dt*128 + ks*16 + khalf*8;
        us8 outw;
        #pragma unroll
        for (int i = 0; i < 8; ++i) outw[i] = f2bf(S[(size_t)(k0+i)*HH + l31]);
        *reinterpret_cast<us8*>(&g_kbs[(size_t)t*8]) = outw;
    } else if (bx < 928) {             // ---- k3b: gt_t[d][h] (transposed) ----
        int idx = (bx - 800) * 256 + tid;   // < 32768
        int h = idx & 31;
        int dist = idx >> 5;
        float cm = bias[4*HH + h];
        float sig = cm*cm + 1e-4f;
        float dd = (float)dist;
        g_gt[idx] = __expf(-sig * dd * dd);   // g_gt[dist*32 + h]
    } else {                           // ---- k3: conv k in B-frag order ----
        int idx3 = bx - 928;           // 0..1559
        int xi  = idx3 & 7;
        int rem = idx3 >> 3;           // 0..194
        int w   = rem % 65;
        int z   = rem / 65;
        int idx = xi * 256 + tid;      // 0..2047
        const int lane = idx & 63;
        const int ks   = (idx >> 6) & 7;
        const int dt   = idx >> 9;
        const int h    = lane & 31;
        const int d8   = dt*128 + ks*16 + (lane >> 5)*8;

        const float c0 = 0.01f;
        const float p = pos[w];
        int ai, mi, vi;
        if (z == 0)      { ai = 0; mi = 0;  vi = 1; }
        else if (z == 1) { ai = 1; mi = -1; vi = 2; }
        else             { ai = 2; mi = 3;  vi = 4; }

        us8 outw;
        #pragma unroll
        for (int i = 0; i < 8; ++i) {
            int d = d8 + i;
            float a    = ampl[(size_t)ai*DD*HH + d*HH + h];
            float mean = (mi >= 0) ? inp[mi*DD + d] * outv[mi*HH + h] : 0.f;
            float iv   = fabsf(inp[vi*DD + d] * outv[vi*HH + h]) + c0;
            float tt = p - mean;
            outw[i] = f2bf(__expf(-iv * tt * tt) * a);
        }
        *reinterpret_cast<us8*>(&g_kb2[((((size_t)z*WW + w)*4 + dt)*8 + ks)*512 + (size_t)lane*8]) = outw;
    }
}

// ================ K2: cf0/cf1 via MFMA, 32-row tiles, 1024 blocks ================
// grid (nt=4, mt=128, z=2); block 256 = 4 waves; wave = n-quadrant (32 cols), one 32x32 acc.
__global__ __launch_bounds__(256) void k2_mfma() {
    const int nt = blockIdx.x;
    const int mt = blockIdx.y;
    const int z  = blockIdx.z;
    const int t  = threadIdx.x;
    const int wave = t >> 6, lane = t & 63;
    const int l31 = lane & 31, khalf = lane >> 5;
    const int n0 = nt*128 + wave*32;
    const int m_base = mt*32;

    __shared__ __align__(16) unsigned short smem[32*128];  // 8 KB A tile (swizzled)

    f32x16 acc;
    #pragma unroll
    for (int i = 0; i < 16; ++i) acc[i] = 0.f;

    const unsigned short* __restrict__ bptr =
        g_knt + ((size_t)z*DD + n0 + l31)*FCC + khalf*8;

    for (int kc = 0; kc < 4; ++kc) {
        __syncthreads();
        const unsigned short* __restrict__ src = g_oefb + (size_t)m_base*FCC + kc*128;
        #pragma unroll
        for (int c = 0; c < 2; ++c) {          // 512 chunks = 32 rows x 16 slots
            int q = c*256 + t;
            int row = q >> 4, slot = q & 15;
            int4 v = *reinterpret_cast<const int4*>(src + (size_t)row*FCC + slot*8);
            int off = row*256 + ((slot*16) ^ ((row & 15) << 4));
            *reinterpret_cast<int4*>((char*)smem + off) = v;
        }
        __syncthreads();
        #pragma unroll
        for (int ks = 0; ks < 8; ++ks) {
            bf16x8 bf = *reinterpret_cast<const bf16x8*>(bptr + kc*128 + ks*16);
            int dby = ks*32 + khalf*16;
            int r = l31;
            bf16x8 a = *reinterpret_cast<const bf16x8*>(
                (char*)smem + r*256 + (dby ^ ((r & 15) << 4)));
            acc = __builtin_amdgcn_mfma_f32_32x32x16_bf16(a, bf, acc, 0, 0, 0);
        }
    }

    #pragma unroll
    for (int reg = 0; reg < 16; ++reg) {
        int rowf = (reg & 3) + 8*(reg >> 2) + 4*khalf;
        int m = m_base + rowf;
        int b_ = m >> 10, l_ = m & 1023;
        g_fpad[((size_t)(z*BB + b_)*LPAD + 32 + l_)*DD + n0 + l31] = f2bf(acc[reg]);
    }
}

// ================ KHEAVY: k4 [0,768) XCD-swizzled / k6 [768,1280) b-shared / k5 [1280,1408) ================
__global__ __launch_bounds__(256) void kheavy() {
    __shared__ __align__(16) char smem_raw[32768];
    const int bx = blockIdx.x;
    const int t  = threadIdx.x;

    if (bx < 768) {
        // ---------- k4: MFMA conv-GEMM, XCD-aware (z,dq)-slice clustering (R12/R14-proven) ----------
        const int xcd = bx & 7;
        const int j8  = bx >> 3;            // 0..95
        const int gidx = xcd*96 + j8;       // slice-ordered global index
        const int zdq = gidx >> 6;          // 0..11
        const int g   = gidx & 63;
        const int lt = g & 15;
        const int b  = g >> 4;
        const int z  = zdq >> 2;
        const int dq = zdq & 3;
        const int fz = (z == 1) ? 1 : 0;
        const int wave = t >> 6, lane = t & 63;
        const int l31 = lane & 31, khalf = lane >> 5;

        const int wbeg = (wave == 0) ? 0 : 17 + (wave - 1)*16;
        const int wend = (wave == 0) ? 17 : wbeg + 16;

        f32x16 acc0, acc1;
        #pragma unroll
        for (int i = 0; i < 16; ++i) { acc0[i] = 0.f; acc1[i] = 0.f; }

        const unsigned short* src =
            g_fpad + ((size_t)(fz*BB + b)*LPAD + lt*64) * DD + dq*128;
        #pragma unroll
        for (int c = 0; c < 8; ++c) {
            int q = c*256 + t;
            int row = q >> 4, slot = q & 15;
            int4 v = *reinterpret_cast<const int4*>(src + (size_t)row*DD + slot*8);
            int off = row*256 + ((slot*16) ^ ((row & 15) << 4));
            *reinterpret_cast<int4*>(smem_raw + off) = v;
        }
        __syncthreads();

        for (int w = wbeg; w < wend; ++w) {
            const unsigned short* kbw =
                g_kb2 + ((((size_t)z*WW + w)*4 + dq)*8)*512;
            const int r0 = l31 + w;
            const int r1 = r0 + 32;
            #pragma unroll
            for (int ks = 0; ks < 8; ++ks) {
                bf16x8 bf = *reinterpret_cast<const bf16x8*>(kbw + ks*512 + lane*8);
                int dby = ks*32 + khalf*16;
                bf16x8 a0 = *reinterpret_cast<const bf16x8*>(
                    smem_raw + r0*256 + (dby ^ ((r0 & 15) << 4)));
                bf16x8 a1 = *reinterpret_cast<const bf16x8*>(
                    smem_raw + r1*256 + (dby ^ ((r1 & 15) << 4)));
                acc0 = __builtin_amdgcn_mfma_f32_32x32x16_bf16(a0, bf, acc0, 0, 0, 0);
                acc1 = __builtin_amdgcn_mfma_f32_32x32x16_bf16(a1, bf, acc1, 0, 0, 0);
            }
        }

        __syncthreads();               // all smem A-tile reads done
        float* red = (float*)smem_raw; // 4 waves × 2048 floats = 32 KB
        #pragma unroll
        for (int reg = 0; reg < 16; ++reg) {
            int row = (reg & 3) + 8*(reg >> 2) + 4*khalf;
            red[wave*2048 + row*32 + l31]        = acc0[reg];
            red[wave*2048 + (32 + row)*32 + l31] = acc1[reg];
        }
        __syncthreads();
        float* outp = g_actsp[dq] + (size_t)z*BLH + ((size_t)b*LL + lt*64)*HH;
        #pragma unroll
        for (int j = 0; j < 8; ++j) {
            int i = j*256 + t;
            float sum = red[i] + red[2048 + i] + red[4096 + i] + red[6144 + i];
            outp[i] = sum;
        }
    } else if (bx < 1280) {
        // ---------- k6: Toeplitz, b-shared (4 fmaf per gt load), window-quarter split (R14) ----------
        float* mlT = (float*)smem_raw;  // mlT[<=180][4] < 3 KB
        const int g  = bx - 768;
        const int jq = g >> 7;          // 0..3 window quarter
        const int ib = g & 127;
        const int i0 = ib * 8;

        int wlo = i0 - 352; if (wlo < 0) wlo = 0; else wlo &= ~3;
        int whi = i0 + 360; if (whi > 1024) whi = 1024; else whi = (whi + 3) & ~3;
        int qstep = (((whi - wlo) + 15) >> 4) << 2;
        int qlo = wlo + jq*qstep;
        int qhi = qlo + qstep; if (qhi > whi) qhi = whi;
        int qn = qhi - qlo; if (qn < 0) qn = 0;

        for (int idx = t; idx < qn*4; idx += 256) {
            int jj = idx >> 2, b = idx & 3;
            mlT[jj*4 + b] = g_m[b*LL + qlo + jj];
        }
        __syncthreads();

        const int h = t & 31;
        const int i = i0 + (t >> 5);
        const float* __restrict__ gtt = g_gt;
        float a0 = 0.f, a1 = 0.f, a2 = 0.f, a3 = 0.f;
        #pragma unroll 2
        for (int jj = 0; jj < qn; ++jj) {
            int j = qlo + jj;
            int c = i - j; int d = c < 0 ? -c : c;
            float gv = gtt[d*HH + h];
            float4 mv = *reinterpret_cast<const float4*>(&mlT[jj*4]);
            a0 = fmaf(gv, mv.x, a0);
            a1 = fmaf(gv, mv.y, a1);
            a2 = fmaf(gv, mv.z, a2);
            a3 = fmaf(gv, mv.w, a3);
        }
        float* vs = g_vsum4[jq];
        vs[((size_t)(0*LL + i))*HH + h] = a0;
        vs[((size_t)(1*LL + i))*HH + h] = a1;
        vs[((size_t)(2*LL + i))*HH + h] = a2;
        vs[((size_t)(3*LL + i))*HH + h] = a3;
    } else {
        // ---------- k5: small GEMMs via MFMA (R14, unchanged) ----------
        const int g = bx - 1280;
        const int mt = g & 31;
        const int o  = g >> 5;
        const int wave = t >> 6, lane = t & 63;
        const int l31 = lane & 31, khalf = lane >> 5;

        const unsigned short* src;
        if (o == 3) {
            src = g_oefb + (size_t)mt*128*FCC;
        } else {
            const int fz = (o == 1) ? 0 : 1;
            const int m0 = mt*128;
            const int b_ = m0 >> 10, l0 = m0 & 1023;
            src = g_fpad + ((size_t)(fz*BB + b_)*LPAD + 32 + l0)*DD;
        }

        f32x16 acc;
        #pragma unroll
        for (int i = 0; i < 16; ++i) acc[i] = 0.f;

        for (int kc = 0; kc < 4; ++kc) {
            __syncthreads();
            const unsigned short* s2 = src + kc*128;
            #pragma unroll
            for (int c = 0; c < 8; ++c) {
                int q = c*256 + t;
                int row = q >> 4, slot = q & 15;
                int4 v = *reinterpret_cast<const int4*>(s2 + (size_t)row*512 + slot*8);
                int off = row*256 + ((slot*16) ^ ((row & 15) << 4));
                *reinterpret_cast<int4*>(smem_raw + off) = v;
            }
            __syncthreads();
            #pragma unroll
            for (int ks = 0; ks < 8; ++ks) {
                bf16x8 bf = *reinterpret_cast<const bf16x8*>(
                    &g_kbs[((((size_t)o*4 + kc)*8 + ks)*64 + lane)*8]);
                int dby = ks*32 + khalf*16;
                int r = wave*32 + l31;
                bf16x8 a = *reinterpret_cast<const bf16x8*>(
                    smem_raw + r*256 + (dby ^ ((r & 15) << 4)));
                acc = __builtin_amdgcn_mfma_f32_32x32x16_bf16(a, bf, acc, 0, 0, 0);
            }
        }

        float* outp = g_small + (size_t)o*BLH + ((size_t)mt*128 + wave*32)*HH;
        #pragma unroll
        for (int reg = 0; reg < 16; ++reg) {
            int row = (reg & 3) + 8*(reg >> 2) + 4*khalf;
            outp[(size_t)row*HH + l31] = acc[reg];
        }
    }
}

// ================ K7: final combine (4 actsp slots + 4 vsum slots) ================
__global__ __launch_bounds__(256) void k7_final(const float* __restrict__ masks,
                                                const float* __restrict__ bias,
                                                float* __restrict__ out) {
    int idx = blockIdx.x * 256 + threadIdx.x;
    int r = idx >> 5, h = idx & 31;
    float a0 = 0.f, a1 = 0.f, a2 = 0.f;
    #pragma unroll
    for (int s = 0; s < 4; ++s) {
        a0 += g_actsp[s][idx];
        a1 += g_actsp[s][BLH + idx];
        a2 += g_actsp[s][2*BLH + idx];
    }
    float rdf = (a0 + bias[0*HH + h]) * a1
              + a2 * (g_small[idx] + bias[2*HH + h])
              + (g_small[BLH + idx] + bias[1*HH + h]) * g_small[2*BLH + idx];
    float pp = g_small[3*BLH + idx] + bias[3*HH + h];
    float vc = g_m[r] * (g_vsum4[0][idx] + g_vsum4[1][idx] + g_vsum4[2][idx] + g_vsum4[3][idx]);
    out[idx] = vc * pp * rdf * masks[r];
}

extern "C" void kernel_launch(void* const* d_in, const int* in_sizes, int n_in,
                              void* d_out, int out_size, void* d_ws, size_t ws_size,
                              hipStream_t stream) {
    (void)in_sizes; (void)n_in; (void)d_ws; (void)ws_size; (void)out_size;
    const float* x_embeds = (const float*)d_in[0];
    const float* latent   = (const float*)d_in[1];
    const float* masks    = (const float*)d_in[2];
    const float* pos      = (const float*)d_in[3];
    const float* x        = (const float*)d_in[4];
    const float* ampl     = (const float*)d_in[5];
    const float* inp      = (const float*)d_in[6];
    const float* outv     = (const float*)d_in[7];
    const float* bias     = (const float*)d_in[8];
    const float* pdw      = (const float*)d_in[9];
    const float* knn      = (const float*)d_in[10];
    float* out = (float*)d_out;

    hipLaunchKernelGGL(kprep, dim3(2488), dim3(256), 0, stream,
                       x_embeds, latent, masks, x, ampl, inp, outv, pos, bias, pdw, knn);
    hipLaunchKernelGGL(k2_mfma, dim3(4, 128, 2), dim3(256), 0, stream);
    hipLaunchKernelGGL(kheavy, dim3(1408), dim3(256), 0, stream);
    hipLaunchKernelGGL(k7_final, dim3(BLH/256), dim3(256), 0, stream, masks, bias, out);
}

// Round 19
// 77.514 us; speedup vs baseline: 1.1664x; 1.0710x over previous
//
#include <hip/hip_runtime.h>
#include <hip/hip_bf16.h>

// Problem constants
#define BB 4
#define LL 1024
#define NFE 480
#define HH 32
#define FCC 512
#define DD 512
#define WW 65
#define BL (BB*LL)          // 4096
#define BLH (BL*HH)         // 131072
#define LPAD 1088           // 1024 + 2*32 halo

typedef short bf16x8 __attribute__((ext_vector_type(8)));
typedef float f32x16 __attribute__((ext_vector_type(16)));
typedef unsigned short us8 __attribute__((ext_vector_type(8)));

__device__ inline unsigned short f2bf(float x) {
    union { float f; unsigned u; } v; v.f = x;
    unsigned r = v.u + 0x7FFFu + ((v.u >> 16) & 1u);
    return (unsigned short)(r >> 16);
}

// Static device scratch
__device__ __align__(16) unsigned short g_oefb[BL*FCC];   // bf16 concat(x_embeds, cls)
__device__ __align__(16) unsigned short g_knt[2*DD*FCC];  // bf16 knn^T [z][n][k]
__device__ float  g_m[BL];
__device__ __align__(16) unsigned short g_fpad[2*BB*LPAD*DD];   // bf16 cf0/cf1, zero-padded rows
__device__ __align__(16) unsigned short g_kb2[(size_t)3*WW*4*8*64*8]; // conv k in B-frag order
__device__ __align__(16) unsigned short g_kbs[4*4*8*64*8];      // small-GEMM B in frag order
__device__ float  g_actsp[4][3*BLH];    // per-dq partials (waves pre-reduced in-block)
__device__ float  g_small[4*BLH];
__device__ float  g_gt[HH*LL];          // TRANSPOSED: gt_t[d][h], h contiguous
__device__ float  g_vsum4[4][BLH];      // per-window-quarter partials

// ================ KPREP: fused prep ================
__global__ __launch_bounds__(256) void kprep(const float* __restrict__ x_embeds,
                                             const float* __restrict__ latent,
                                             const float* __restrict__ masks,
                                             const float* __restrict__ x,
                                             const float* __restrict__ ampl,
                                             const float* __restrict__ inp,
                                             const float* __restrict__ outv,
                                             const float* __restrict__ pos,
                                             const float* __restrict__ bias,
                                             const float* __restrict__ pdw,
                                             const float* __restrict__ knn) {
    const int bx = blockIdx.x;
    const int tid = threadIdx.x;

    if (bx < 512) {                    // ---- k1: softmax + concat + m ----
        const int row0 = bx * 8;
        const int r    = row0 + (tid >> 5);
        const int lane = tid & 31;

        const float mask = masks[r];
        float v = latent[r*HH + lane] * mask;
        float mx = v;
        #pragma unroll
        for (int off = 16; off > 0; off >>= 1) mx = fmaxf(mx, __shfl_xor(mx, off, 32));
        float e = __expf(v - mx);
        float s = e;
        #pragma unroll
        for (int off = 16; off > 0; off >>= 1) s += __shfl_xor(s, off, 32);
        g_oefb[r*FCC + NFE + lane] = f2bf(e / s * mask);

        if (lane == 0) g_m[r] = mask + x[r*23 + 21] + x[r*23 + 22];

        for (int idx = tid; idx < 8*NFE; idx += 256) {
            int rr = idx / NFE, c = idx - rr*NFE;
            g_oefb[(row0+rr)*FCC + c] = f2bf(x_embeds[(row0+rr)*NFE + c]);
        }
    } else if (bx < 640) {             // ---- k0: zero g_fpad halos ----
        int idx = (bx - 512) * 256 + tid;
        int fzb = idx >> 12;
        int rem = idx & 4095;
        int rowi = rem >> 6;
        int col8 = rem & 63;
        int row = (rowi < 32) ? rowi : (1024 + rowi);
        int4 z = make_int4(0,0,0,0);
        *reinterpret_cast<int4*>(&g_fpad[((size_t)fzb*LPAD + row)*DD + col8*8]) = z;
    } else if (bx < 768) {             // ---- k3c: knn -> bf16 transpose ----
        __shared__ unsigned short tile[64][65];
        int idx2 = bx - 640;
        const int k0 = (idx2 & 7) * 64;
        const int n0 = ((idx2 >> 3) & 7) * 64;
        const int z  = idx2 >> 6;
        const float* __restrict__ src = knn + (size_t)z*FCC*DD;
        #pragma unroll 4
        for (int i = 0; i < 16; ++i) {
            int idx = i*256 + tid;
            int kk = idx >> 6, nn = idx & 63;
            tile[kk][nn] = f2bf(src[(size_t)(k0+kk)*DD + n0+nn]);
        }
        __syncthreads();
        #pragma unroll 4
        for (int i = 0; i < 16; ++i) {
            int idx = i*256 + tid;
            int nn = idx >> 6, kk = idx & 63;
            g_knt[((size_t)z*DD + n0+nn)*FCC + k0+kk] = tile[kk][nn];
        }
    } else if (bx < 800) {             // ---- k3d: small-GEMM B frags ----
        int t = (bx - 768)*256 + tid;
        int lane = t & 63;
        int ks = (t >> 6) & 7;
        int dt = (t >> 9) & 3;
        int o  = t >> 11;
        int l31 = lane & 31, khalf = lane >> 5;
        const float* S = (o == 0) ? ampl + 1*DD*HH :
                         (o == 1) ? ampl + 3*DD*HH :
                         (o == 2) ? ampl + 4*DD*HH : pdw;
        int k0 = dt*128 + ks*16 + khalf*8;
        us8 outw;
        #pragma unroll
        for (int i = 0; i < 8; ++i) outw[i] = f2bf(S[(size_t)(k0+i)*HH + l31]);
        *reinterpret_cast<us8*>(&g_kbs[(size_t)t*8]) = outw;
    } else if (bx < 928) {             // ---- k3b: gt_t[d][h] (transposed) ----
        int idx = (bx - 800) * 256 + tid;   // < 32768
        int h = idx & 31;
        int dist = idx >> 5;
        float cm = bias[4*HH + h];
        float sig = cm*cm + 1e-4f;
        float dd = (float)dist;
        g_gt[idx] = __expf(-sig * dd * dd);   // g_gt[dist*32 + h]
    } else {                           // ---- k3: conv k in B-frag order ----
        int idx3 = bx - 928;           // 0..1559
        int xi  = idx3 & 7;
        int rem = idx3 >> 3;           // 0..194
        int w   = rem % 65;
        int z   = rem / 65;
        int idx = xi * 256 + tid;      // 0..2047
        const int lane = idx & 63;
        const int ks   = (idx >> 6) & 7;
        const int dt   = idx >> 9;
        const int h    = lane & 31;
        const int d8   = dt*128 + ks*16 + (lane >> 5)*8;

        const float c0 = 0.01f;
        const float p = pos[w];
        int ai, mi, vi;
        if (z == 0)      { ai = 0; mi = 0;  vi = 1; }
        else if (z == 1) { ai = 1; mi = -1; vi = 2; }
        else             { ai = 2; mi = 3;  vi = 4; }

        us8 outw;
        #pragma unroll
        for (int i = 0; i < 8; ++i) {
            int d = d8 + i;
            float a    = ampl[(size_t)ai*DD*HH + d*HH + h];
            float mean = (mi >= 0) ? inp[mi*DD + d] * outv[mi*HH + h] : 0.f;
            float iv   = fabsf(inp[vi*DD + d] * outv[vi*HH + h]) + c0;
            float tt = p - mean;
            outw[i] = f2bf(__expf(-iv * tt * tt) * a);
        }
        *reinterpret_cast<us8*>(&g_kb2[((((size_t)z*WW + w)*4 + dt)*8 + ks)*512 + (size_t)lane*8]) = outw;
    }
}

// ================ K2: cf0/cf1 via MFMA (64-row tiles, 512 blocks — R14-proven) ================
__global__ __launch_bounds__(256) void k2_mfma() {
    const int nt = blockIdx.x;
    const int mt = blockIdx.y;
    const int z  = blockIdx.z;
    const int t  = threadIdx.x;
    const int wave = t >> 6, lane = t & 63;
    const int l31 = lane & 31, khalf = lane >> 5;
    const int n0 = nt*128 + wave*32;
    const int m_base = mt*64;

    __shared__ __align__(16) unsigned short smem[64*128];  // 16 KB A tile (swizzled)

    f32x16 acc[2];
    #pragma unroll
    for (int mti = 0; mti < 2; ++mti)
        #pragma unroll
        for (int i = 0; i < 16; ++i) acc[mti][i] = 0.f;

    const unsigned short* __restrict__ bptr =
        g_knt + ((size_t)z*DD + n0 + l31)*FCC + khalf*8;

    for (int kc = 0; kc < 4; ++kc) {
        __syncthreads();
        const unsigned short* __restrict__ src = g_oefb + (size_t)m_base*FCC + kc*128;
        #pragma unroll
        for (int c = 0; c < 4; ++c) {
            int q = c*256 + t;
            int row = q >> 4, slot = q & 15;
            int4 v = *reinterpret_cast<const int4*>(src + (size_t)row*FCC + slot*8);
            int off = row*256 + ((slot*16) ^ ((row & 15) << 4));
            *reinterpret_cast<int4*>((char*)smem + off) = v;
        }
        __syncthreads();
        #pragma unroll
        for (int ks = 0; ks < 8; ++ks) {
            bf16x8 bf = *reinterpret_cast<const bf16x8*>(bptr + kc*128 + ks*16);
            int dby = ks*32 + khalf*16;
            #pragma unroll
            for (int mti = 0; mti < 2; ++mti) {
                int r = mti*32 + l31;
                bf16x8 a = *reinterpret_cast<const bf16x8*>(
                    (char*)smem + r*256 + (dby ^ ((r & 15) << 4)));
                acc[mti] = __builtin_amdgcn_mfma_f32_32x32x16_bf16(a, bf, acc[mti], 0, 0, 0);
            }
        }
    }

    #pragma unroll
    for (int mti = 0; mti < 2; ++mti) {
        #pragma unroll
        for (int reg = 0; reg < 16; ++reg) {
            int rowf = (reg & 3) + 8*(reg >> 2) + 4*khalf;
            int m = m_base + mti*32 + rowf;
            int b_ = m >> 10, l_ = m & 1023;
            g_fpad[((size_t)(z*BB + b_)*LPAD + 32 + l_)*DD + n0 + l31] = f2bf(acc[mti][reg]);
        }
    }
}

// ================ KHEAVY: k4 [0,768) XCD-swizzled / k6 [768,1280) b-shared / k5 [1280,1408) ================
__global__ __launch_bounds__(256) void kheavy() {
    __shared__ __align__(16) char smem_raw[32768];
    const int bx = blockIdx.x;
    const int t  = threadIdx.x;

    if (bx < 768) {
        // ---------- k4: MFMA conv-GEMM, XCD-aware (z,dq)-slice clustering ----------
        const int xcd = bx & 7;
        const int j8  = bx >> 3;            // 0..95
        const int gidx = xcd*96 + j8;       // slice-ordered global index
        const int zdq = gidx >> 6;          // 0..11
        const int g   = gidx & 63;
        const int lt = g & 15;
        const int b  = g >> 4;
        const int z  = zdq >> 2;
        const int dq = zdq & 3;
        const int fz = (z == 1) ? 1 : 0;
        const int wave = t >> 6, lane = t & 63;
        const int l31 = lane & 31, khalf = lane >> 5;

        const int wbeg = (wave == 0) ? 0 : 17 + (wave - 1)*16;
        const int wend = (wave == 0) ? 17 : wbeg + 16;

        f32x16 acc0, acc1;
        #pragma unroll
        for (int i = 0; i < 16; ++i) { acc0[i] = 0.f; acc1[i] = 0.f; }

        const unsigned short* src =
            g_fpad + ((size_t)(fz*BB + b)*LPAD + lt*64) * DD + dq*128;
        #pragma unroll
        for (int c = 0; c < 8; ++c) {
            int q = c*256 + t;
            int row = q >> 4, slot = q & 15;
            int4 v = *reinterpret_cast<const int4*>(src + (size_t)row*DD + slot*8);
            int off = row*256 + ((slot*16) ^ ((row & 15) << 4));
            *reinterpret_cast<int4*>(smem_raw + off) = v;
        }
        __syncthreads();

        for (int w = wbeg; w < wend; ++w) {
            const unsigned short* kbw =
                g_kb2 + ((((size_t)z*WW + w)*4 + dq)*8)*512;
            const int r0 = l31 + w;
            const int r1 = r0 + 32;
            #pragma unroll
            for (int ks = 0; ks < 8; ++ks) {
                bf16x8 bf = *reinterpret_cast<const bf16x8*>(kbw + ks*512 + lane*8);
                int dby = ks*32 + khalf*16;
                bf16x8 a0 = *reinterpret_cast<const bf16x8*>(
                    smem_raw + r0*256 + (dby ^ ((r0 & 15) << 4)));
                bf16x8 a1 = *reinterpret_cast<const bf16x8*>(
                    smem_raw + r1*256 + (dby ^ ((r1 & 15) << 4)));
                acc0 = __builtin_amdgcn_mfma_f32_32x32x16_bf16(a0, bf, acc0, 0, 0, 0);
                acc1 = __builtin_amdgcn_mfma_f32_32x32x16_bf16(a1, bf, acc1, 0, 0, 0);
            }
        }

        __syncthreads();               // all smem A-tile reads done
        float* red = (float*)smem_raw; // 4 waves × 2048 floats = 32 KB
        #pragma unroll
        for (int reg = 0; reg < 16; ++reg) {
            int row = (reg & 3) + 8*(reg >> 2) + 4*khalf;
            red[wave*2048 + row*32 + l31]        = acc0[reg];
            red[wave*2048 + (32 + row)*32 + l31] = acc1[reg];
        }
        __syncthreads();
        float* outp = g_actsp[dq] + (size_t)z*BLH + ((size_t)b*LL + lt*64)*HH;
        #pragma unroll
        for (int j = 0; j < 8; ++j) {
            int i = j*256 + t;
            float sum = red[i] + red[2048 + i] + red[4096 + i] + red[6144 + i];
            outp[i] = sum;
        }
    } else if (bx < 1280) {
        // ---------- k6: Toeplitz, b-shared (4 fmaf per gt load), window-quarter split ----------
        float* mlT = (float*)smem_raw;  // mlT[<=180][4] < 3 KB
        const int g  = bx - 768;
        const int jq = g >> 7;          // 0..3 window quarter
        const int ib = g & 127;
        const int i0 = ib * 8;

        int wlo = i0 - 352; if (wlo < 0) wlo = 0; else wlo &= ~3;
        int whi = i0 + 360; if (whi > 1024) whi = 1024; else whi = (whi + 3) & ~3;
        int qstep = (((whi - wlo) + 15) >> 4) << 2;   // ceil(len/4) to mult of 4
        int qlo = wlo + jq*qstep;
        int qhi = qlo + qstep; if (qhi > whi) qhi = whi;
        int qn = qhi - qlo; if (qn < 0) qn = 0;

        for (int idx = t; idx < qn*4; idx += 256) {
            int jj = idx >> 2, b = idx & 3;
            mlT[jj*4 + b] = g_m[b*LL + qlo + jj];
        }
        __syncthreads();

        const int h = t & 31;
        const int i = i0 + (t >> 5);
        const float* __restrict__ gtt = g_gt;
        float a0 = 0.f, a1 = 0.f, a2 = 0.f, a3 = 0.f;
        #pragma unroll 2
        for (int jj = 0; jj < qn; ++jj) {
            int j = qlo + jj;
            int c = i - j; int d = c < 0 ? -c : c;
            float gv = gtt[d*HH + h];
            float4 mv = *reinterpret_cast<const float4*>(&mlT[jj*4]);
            a0 = fmaf(gv, mv.x, a0);
            a1 = fmaf(gv, mv.y, a1);
            a2 = fmaf(gv, mv.z, a2);
            a3 = fmaf(gv, mv.w, a3);
        }
        float* vs = g_vsum4[jq];
        vs[((size_t)(0*LL + i))*HH + h] = a0;
        vs[((size_t)(1*LL + i))*HH + h] = a1;
        vs[((size_t)(2*LL + i))*HH + h] = a2;
        vs[((size_t)(3*LL + i))*HH + h] = a3;
    } else {
        // ---------- k5: small GEMMs via MFMA ----------
        const int g = bx - 1280;
        const int mt = g & 31;
        const int o  = g >> 5;
        const int wave = t >> 6, lane = t & 63;
        const int l31 = lane & 31, khalf = lane >> 5;

        const unsigned short* src;
        if (o == 3) {
            src = g_oefb + (size_t)mt*128*FCC;
        } else {
            const int fz = (o == 1) ? 0 : 1;
            const int m0 = mt*128;
            const int b_ = m0 >> 10, l0 = m0 & 1023;
            src = g_fpad + ((size_t)(fz*BB + b_)*LPAD + 32 + l0)*DD;
        }

        f32x16 acc;
        #pragma unroll
        for (int i = 0; i < 16; ++i) acc[i] = 0.f;

        for (int kc = 0; kc < 4; ++kc) {
            __syncthreads();
            const unsigned short* s2 = src + kc*128;
            #pragma unroll
            for (int c = 0; c < 8; ++c) {
                int q = c*256 + t;
                int row = q >> 4, slot = q & 15;
                int4 v = *reinterpret_cast<const int4*>(s2 + (size_t)row*512 + slot*8);
                int off = row*256 + ((slot*16) ^ ((row & 15) << 4));
                *reinterpret_cast<int4*>(smem_raw + off) = v;
            }
            __syncthreads();
            #pragma unroll
            for (int ks = 0; ks < 8; ++ks) {
                bf16x8 bf = *reinterpret_cast<const bf16x8*>(
                    &g_kbs[((((size_t)o*4 + kc)*8 + ks)*64 + lane)*8]);
                int dby = ks*32 + khalf*16;
                int r = wave*32 + l31;
                bf16x8 a = *reinterpret_cast<const bf16x8*>(
                    smem_raw + r*256 + (dby ^ ((r & 15) << 4)));
                acc = __builtin_amdgcn_mfma_f32_32x32x16_bf16(a, bf, acc, 0, 0, 0);
            }
        }

        float* outp = g_small + (size_t)o*BLH + ((size_t)mt*128 + wave*32)*HH;
        #pragma unroll
        for (int reg = 0; reg < 16; ++reg) {
            int row = (reg & 3) + 8*(reg >> 2) + 4*khalf;
            outp[(size_t)row*HH + l31] = acc[reg];
        }
    }
}

// ================ K7: final combine (4 actsp slots + 4 vsum slots) ================
__global__ __launch_bounds__(256) void k7_final(const float* __restrict__ masks,
                                                const float* __restrict__ bias,
                                                float* __restrict__ out) {
    int idx = blockIdx.x * 256 + threadIdx.x;
    int r = idx >> 5, h = idx & 31;
    float a0 = 0.f, a1 = 0.f, a2 = 0.f;
    #pragma unroll
    for (int s = 0; s < 4; ++s) {
        a0 += g_actsp[s][idx];
        a1 += g_actsp[s][BLH + idx];
        a2 += g_actsp[s][2*BLH + idx];
    }
    float rdf = (a0 + bias[0*HH + h]) * a1
              + a2 * (g_small[idx] + bias[2*HH + h])
              + (g_small[BLH + idx] + bias[1*HH + h]) * g_small[2*BLH + idx];
    float pp = g_small[3*BLH + idx] + bias[3*HH + h];
    float vc = g_m[r] * (g_vsum4[0][idx] + g_vsum4[1][idx] + g_vsum4[2][idx] + g_vsum4[3][idx]);
    out[idx] = vc * pp * rdf * masks[r];
}

extern "C" void kernel_launch(void* const* d_in, const int* in_sizes, int n_in,
                              void* d_out, int out_size, void* d_ws, size_t ws_size,
                              hipStream_t stream) {
    (void)in_sizes; (void)n_in; (void)d_ws; (void)ws_size; (void)out_size;
    const float* x_embeds = (const float*)d_in[0];
    const float* latent   = (const float*)d_in[1];
    const float* masks    = (const float*)d_in[2];
    const float* pos      = (const float*)d_in[3];
    const float* x        = (const float*)d_in[4];
    const float* ampl     = (const float*)d_in[5];
    const float* inp      = (const float*)d_in[6];
    const float* outv     = (const float*)d_in[7];
    const float* bias     = (const float*)d_in[8];
    const float* pdw      = (const float*)d_in[9];
    const float* knn      = (const float*)d_in[10];
    float* out = (float*)d_out;

    hipLaunchKernelGGL(kprep, dim3(2488), dim3(256), 0, stream,
                       x_embeds, latent, masks, x, ampl, inp, outv, pos, bias, pdw, knn);
    hipLaunchKernelGGL(k2_mfma, dim3(4, 64, 2), dim3(256), 0, stream);
    hipLaunchKernelGGL(kheavy, dim3(1408), dim3(256), 0, stream);
    hipLaunchKernelGGL(k7_final, dim3(BLH/256), dim3(256), 0, stream, masks, bias, out);
}